// Round 7
// baseline (3211.860 us; speedup 1.0000x reference)
//
#include <hip/hip_runtime.h>
#include <hip/hip_cooperative_groups.h>

namespace cg = cooperative_groups;

#define FEATS    64
#define CLASSES  16
#define EMB_DIM  7
#define ADJ_HID  11
#define DIFF     0.9f

#define COOP_GRID 1024

__device__ inline float bf2f(unsigned short u) {
    return __uint_as_float(((unsigned int)u) << 16);
}
__device__ inline unsigned short f2bf(float f) {
    unsigned int u = __float_as_uint(f);
    return (unsigned short)((u + 0x7FFFu + ((u >> 16) & 1u)) >> 16);
}

// ---------------- graph preprocessing ----------------

__global__ __launch_bounds__(256) void k_deg(const int* __restrict__ dst, int* __restrict__ deg, int e) {
    int i = blockIdx.x * 256 + threadIdx.x;
    if (i < e) atomicAdd(&deg[dst[i]], 1);
}

__global__ __launch_bounds__(256) void k_invs(const int* __restrict__ deg, float* __restrict__ invs, int n) {
    int i = blockIdx.x * 256 + threadIdx.x;
    if (i < n) { int d = deg[i]; invs[i] = d > 0 ? rsqrtf((float)d) : 0.f; }
}

__global__ __launch_bounds__(256) void k_scan1(const int* __restrict__ deg, int* __restrict__ rowptr,
                                               int* __restrict__ bsum, int n) {
    __shared__ int s[256];
    int tid = threadIdx.x;
    int i = blockIdx.x * 256 + tid;
    int v = (i < n) ? deg[i] : 0;
    s[tid] = v; __syncthreads();
    for (int ofs = 1; ofs < 256; ofs <<= 1) {
        int t = (tid >= ofs) ? s[tid - ofs] : 0;
        __syncthreads(); s[tid] += t; __syncthreads();
    }
    if (i < n) rowptr[i] = s[tid] - v;
    if (tid == 255) bsum[blockIdx.x] = s[255];
}

__global__ __launch_bounds__(256) void k_scan2(int* __restrict__ bsum, int nb) {
    __shared__ int s[256];
    int tid = threadIdx.x;
    int v = (tid < nb) ? bsum[tid] : 0;
    s[tid] = v; __syncthreads();
    for (int ofs = 1; ofs < 256; ofs <<= 1) {
        int t = (tid >= ofs) ? s[tid - ofs] : 0;
        __syncthreads(); s[tid] += t; __syncthreads();
    }
    if (tid < nb) bsum[tid] = s[tid] - v;
}

__global__ __launch_bounds__(256) void k_scan3(int* __restrict__ rowptr, const int* __restrict__ bsum,
                                               int n, int e) {
    int i = blockIdx.x * 256 + threadIdx.x;
    if (i < n) rowptr[i] += bsum[i >> 8];
    if (i == n) rowptr[n] = e;
}

__global__ __launch_bounds__(256) void k_scatter(const int* __restrict__ src, const int* __restrict__ dst,
                                                 const float* __restrict__ invs, const int* __restrict__ rowptr,
                                                 int* __restrict__ cnt, int2* __restrict__ edge, int e) {
    int i = blockIdx.x * 256 + threadIdx.x;
    if (i >= e) return;
    int d = dst[i], sv = src[i];
    int pos = rowptr[d] + atomicAdd(&cnt[d], 1);
    edge[pos] = make_int2(sv, __float_as_int(invs[sv] * invs[d]));
}

// ---------------- fp32 -> bf16 cast (x -> xb) ----------------

__global__ __launch_bounds__(256) void k_cast(const float4* __restrict__ in, ushort4* __restrict__ out, int total4) {
    int i = blockIdx.x * 256 + threadIdx.x;
    if (i < total4) {
        float4 v = in[i];
        ushort4 o;
        o.x = f2bf(v.x); o.y = f2bf(v.y); o.z = f2bf(v.z); o.w = f2bf(v.w);
        out[i] = o;
    }
}

// ---------------- conv64 inner body (shared by fused + fallback) ----------------

__device__ inline void conv64_node(const ushort4* __restrict__ zin, const ushort4* __restrict__ h0b,
                                   ushort4* __restrict__ zout, const int* __restrict__ rowptr,
                                   const int2* __restrict__ edge, int node, int lane, int g, int c) {
    int e0 = rowptr[node], e1 = rowptr[node + 1];
    float a0 = 0.f, a1 = 0.f, a2 = 0.f, a3 = 0.f;
    for (int e = e0; e < e1; e += 16) {
        #pragma unroll
        for (int k = 0; k < 4; ++k) {
            int idx = e + k * 4 + g;
            bool ok = idx < e1;
            int2 p = edge[ok ? idx : e0];
            float w = ok ? __int_as_float(p.y) : 0.f;
            ushort4 v = zin[(size_t)p.x * 16 + c];
            a0 = fmaf(w, bf2f(v.x), a0);
            a1 = fmaf(w, bf2f(v.y), a1);
            a2 = fmaf(w, bf2f(v.z), a2);
            a3 = fmaf(w, bf2f(v.w), a3);
        }
    }
    a0 += __shfl_xor(a0, 16); a1 += __shfl_xor(a1, 16);
    a2 += __shfl_xor(a2, 16); a3 += __shfl_xor(a3, 16);
    a0 += __shfl_xor(a0, 32); a1 += __shfl_xor(a1, 32);
    a2 += __shfl_xor(a2, 32); a3 += __shfl_xor(a3, 32);
    if (lane < 16) {
        ushort4 h4 = h0b[(size_t)node * 16 + lane];
        ushort4 o;
        o.x = f2bf(a0 * DIFF + (1.f - DIFF) * bf2f(h4.x));
        o.y = f2bf(a1 * DIFF + (1.f - DIFF) * bf2f(h4.y));
        o.z = f2bf(a2 * DIFF + (1.f - DIFF) * bf2f(h4.z));
        o.w = f2bf(a3 * DIFF + (1.f - DIFF) * bf2f(h4.w));
        zout[(size_t)node * 16 + lane] = o;
    }
}

// fused: all 10 iterations, grid-stride, grid.sync between iters
__global__ __launch_bounds__(256) void k_diffuse64(const ushort4* __restrict__ xb,
                                                   ushort4* __restrict__ zA, ushort4* __restrict__ zB,
                                                   const int* __restrict__ rowptr,
                                                   const int2* __restrict__ edge, int n, int nwaves) {
    cg::grid_group grid = cg::this_grid();
    int gwave = (blockIdx.x * 256 + threadIdx.x) >> 6;
    int lane = threadIdx.x & 63;
    int g = lane >> 4, c = lane & 15;
    for (int it = 0; it < 10; ++it) {
        const ushort4* zin = (it == 0) ? xb : ((it & 1) ? zA : zB);
        ushort4* zout = (it & 1) ? zB : zA;
        for (int node = gwave; node < n; node += nwaves)
            conv64_node(zin, xb, zout, rowptr, edge, node, lane, g, c);
        grid.sync();
    }
}

// fallback: one iteration per dispatch
__global__ __launch_bounds__(256) void k_conv64b(const ushort4* __restrict__ zin, const ushort4* __restrict__ h0b,
                                                 ushort4* __restrict__ zout, const int* __restrict__ rowptr,
                                                 const int2* __restrict__ edge, int n) {
    int wid = (blockIdx.x * 256 + threadIdx.x) >> 6;
    if (wid >= n) return;
    int lane = threadIdx.x & 63;
    conv64_node(zin, h0b, zout, rowptr, edge, wid, lane, lane >> 4, lane & 15);
}

// ---------------- conv16 inner body ----------------

__device__ inline void conv16_node(const float4* __restrict__ zin4, const float4* __restrict__ g04,
                                   float4* __restrict__ zout4, const int* __restrict__ rowptr,
                                   const int2* __restrict__ edge, int node, int lane, int g, int c) {
    int e0 = rowptr[node], e1 = rowptr[node + 1];
    float4 acc; acc.x = acc.y = acc.z = acc.w = 0.f;
    for (int e = e0; e < e1; e += 32) {
        #pragma unroll
        for (int k = 0; k < 2; ++k) {
            int idx = e + k * 16 + g;
            bool ok = idx < e1;
            int2 p = edge[ok ? idx : e0];
            float w = ok ? __int_as_float(p.y) : 0.f;
            float4 v = zin4[(size_t)p.x * 4 + c];
            acc.x = fmaf(w, v.x, acc.x);
            acc.y = fmaf(w, v.y, acc.y);
            acc.z = fmaf(w, v.z, acc.z);
            acc.w = fmaf(w, v.w, acc.w);
        }
    }
    #pragma unroll
    for (int m = 4; m <= 32; m <<= 1) {
        acc.x += __shfl_xor(acc.x, m);
        acc.y += __shfl_xor(acc.y, m);
        acc.z += __shfl_xor(acc.z, m);
        acc.w += __shfl_xor(acc.w, m);
    }
    if (lane < 4) {
        float4 h = g04[(size_t)node * 4 + lane];
        float4 o;
        o.x = acc.x * DIFF + (1.f - DIFF) * h.x;
        o.y = acc.y * DIFF + (1.f - DIFF) * h.y;
        o.z = acc.z * DIFF + (1.f - DIFF) * h.z;
        o.w = acc.w * DIFF + (1.f - DIFF) * h.w;
        zout4[(size_t)node * 4 + lane] = o;
    }
}

__global__ __launch_bounds__(256) void k_diffuse16(const float4* __restrict__ g0,
                                                   float4* __restrict__ gA, float4* __restrict__ gB,
                                                   float4* __restrict__ dout,
                                                   const int* __restrict__ rowptr,
                                                   const int2* __restrict__ edge, int n, int nwaves) {
    cg::grid_group grid = cg::this_grid();
    int gwave = (blockIdx.x * 256 + threadIdx.x) >> 6;
    int lane = threadIdx.x & 63;
    int g = lane >> 2, c = lane & 3;
    for (int it = 0; it < 10; ++it) {
        const float4* zin = (it == 0) ? g0 : ((it & 1) ? gA : gB);
        float4* zout = (it == 9) ? dout : ((it & 1) ? gB : gA);
        for (int node = gwave; node < n; node += nwaves)
            conv16_node(zin, g0, zout, rowptr, edge, node, lane, g, c);
        grid.sync();
    }
}

__global__ __launch_bounds__(256) void k_conv16(const float4* __restrict__ zin4, const float4* __restrict__ g04,
                                                float4* __restrict__ zout4, const int* __restrict__ rowptr,
                                                const int2* __restrict__ edge, int n) {
    int wid = (blockIdx.x * 256 + threadIdx.x) >> 6;
    if (wid >= n) return;
    int lane = threadIdx.x & 63;
    conv16_node(zin4, g04, zout4, rowptr, edge, wid, lane, lane >> 2, lane & 3);
}

// ---------------- fused pair-MLP + node-MLP, persistent blocks ----------------

#define PM_GRID 512

__global__ __launch_bounds__(256) void k_pairmlp(const unsigned short* __restrict__ z1, const float* __restrict__ x,
                                                 const float* __restrict__ W1, const float* __restrict__ b1,
                                                 const float* __restrict__ W2, const float* __restrict__ b2,
                                                 const float* __restrict__ A1, const float* __restrict__ ab1,
                                                 const float* __restrict__ A2, const float* __restrict__ ab2,
                                                 const float* __restrict__ emb,
                                                 float* __restrict__ g0, int n, int ntiles) {
    __shared__ float W1s[128 * 64];
    __shared__ float W2s[64 * 16];
    __shared__ float in_s[32][128];
    __shared__ float hid[32 * 65];
    __shared__ float eA1T[ADJ_HID * 64];
    __shared__ float a0s[ADJ_HID], a1s[ADJ_HID], a2s[ADJ_HID];
    __shared__ float ab2s;

    int tid = threadIdx.x;
    const ushort4* z4p = (const ushort4*)z1;
    const float4*  x4p = (const float4*)x;

    #pragma unroll
    for (int k = 0; k < 32; ++k) W1s[tid + k * 256] = W1[tid + k * 256];
    #pragma unroll
    for (int k = 0; k < 4; ++k)  W2s[tid + k * 256] = W2[tid + k * 256];
    if (tid < ADJ_HID) { a0s[tid] = A1[tid]; a1s[tid] = A1[ADJ_HID + tid]; a2s[tid] = A2[tid]; }
    if (tid == 0) ab2s = ab2[0];
    for (int idx = tid; idx < ADJ_HID * 64; idx += 256) {
        int h = idx >> 6, c = idx & 63;
        float s = ab1[h];
        #pragma unroll
        for (int j = 0; j < EMB_DIM; j++) s = fmaf(emb[c * EMB_DIM + j], A1[(2 + j) * ADJ_HID + h], s);
        eA1T[idx] = s;
    }
    __syncthreads();

    for (int tile = blockIdx.x; tile < ntiles; tile += PM_GRID) {
        int base = tile * 32;

        #pragma unroll
        for (int j = 0; j < 2; ++j) {
            int e4 = tid + j * 256;
            int nl = e4 >> 4, c4 = e4 & 15;
            int node = base + nl; if (node > n - 1) node = n - 1;
            ushort4 z4 = z4p[(size_t)node * 16 + c4];
            float4  x4 = x4p[(size_t)node * 16 + c4];
            float zf0 = bf2f(z4.x), zf1 = bf2f(z4.y), zf2 = bf2f(z4.z), zf3 = bf2f(z4.w);
            float o0 = ab2s, o1 = ab2s, o2 = ab2s, o3 = ab2s;
            #pragma unroll
            for (int h = 0; h < ADJ_HID; h++) {
                float a0 = a0s[h], a1 = a1s[h], a2 = a2s[h];
                float4 ee = *(const float4*)&eA1T[h * 64 + c4 * 4];
                float t;
                t = fmaf(zf0, a0, fmaf(x4.x, a1, ee.x)); t = fmaxf(t, 0.f); o0 = fmaf(t, a2, o0);
                t = fmaf(zf1, a0, fmaf(x4.y, a1, ee.y)); t = fmaxf(t, 0.f); o1 = fmaf(t, a2, o1);
                t = fmaf(zf2, a0, fmaf(x4.z, a1, ee.z)); t = fmaxf(t, 0.f); o2 = fmaf(t, a2, o2);
                t = fmaf(zf3, a0, fmaf(x4.w, a1, ee.w)); t = fmaxf(t, 0.f); o3 = fmaf(t, a2, o3);
            }
            *(float4*)&in_s[nl][c4 * 4]      = make_float4(o0 * 0.5f, o1 * 0.5f, o2 * 0.5f, o3 * 0.5f);
            *(float4*)&in_s[nl][64 + c4 * 4] = x4;
        }
        __syncthreads();

        {
            int lane = tid & 63, wv = tid >> 6;
            int nb0 = wv * 8;
            float bv = b1[lane];
            float acc[8];
            #pragma unroll
            for (int j = 0; j < 8; ++j) acc[j] = bv;
            #pragma unroll 8
            for (int rb = 0; rb < 128; rb += 4) {
                float w0 = W1s[(rb    ) * 64 + lane];
                float w1 = W1s[(rb + 1) * 64 + lane];
                float w2 = W1s[(rb + 2) * 64 + lane];
                float w3 = W1s[(rb + 3) * 64 + lane];
                #pragma unroll
                for (int j = 0; j < 8; ++j) {
                    float4 iv = *(const float4*)&in_s[nb0 + j][rb];
                    acc[j] = fmaf(iv.w, w3, fmaf(iv.z, w2, fmaf(iv.y, w1, fmaf(iv.x, w0, acc[j]))));
                }
            }
            #pragma unroll
            for (int j = 0; j < 8; ++j) hid[(nb0 + j) * 65 + lane] = fmaxf(acc[j], 0.f);
        }
        __syncthreads();

        {
            int c  = tid & 15;
            int nl = tid >> 4;
            float ac0 = b2[c], ac1 = ac0;
            #pragma unroll
            for (int h = 0; h < 64; ++h) {
                float w = W2s[h * 16 + c];
                ac0 = fmaf(hid[nl * 65 + h],        w, ac0);
                ac1 = fmaf(hid[(nl + 16) * 65 + h], w, ac1);
            }
            int n0 = base + nl, n1 = base + nl + 16;
            if (n0 < n) g0[(size_t)n0 * 16 + c] = ac0;
            if (n1 < n) g0[(size_t)n1 * 16 + c] = ac1;
        }
        __syncthreads();
    }
}

// ---------------- launch ----------------

extern "C" void kernel_launch(void* const* d_in, const int* in_sizes, int n_in,
                              void* d_out, int out_size, void* d_ws, size_t ws_size,
                              hipStream_t stream) {
    const float* x   = (const float*)d_in[0];
    const int*   src = (const int*)d_in[1];
    const int*   dst = (const int*)d_in[2];
    const float* W1  = (const float*)d_in[3];
    const float* b1  = (const float*)d_in[4];
    const float* W2  = (const float*)d_in[5];
    const float* b2  = (const float*)d_in[6];
    const float* A1  = (const float*)d_in[7];
    const float* ab1 = (const float*)d_in[8];
    const float* A2  = (const float*)d_in[9];
    const float* ab2 = (const float*)d_in[10];
    const float* emb = (const float*)d_in[11];

    int n = in_sizes[0] / FEATS;   // 50000
    int e = in_sizes[1];           // 800000

    char* ws = (char*)d_ws;
    size_t off = 0;
    auto alloc = [&](size_t bytes) {
        void* p = ws + off;
        off += bytes;
        off = (off + 255) & ~(size_t)255;
        return p;
    };

    int*     deg    = (int*)    alloc((size_t)n * 4);
    float*   invs   = (float*)  alloc((size_t)n * 4);
    int*     rowptr = (int*)    alloc((size_t)(n + 1) * 4);
    int*     cnt    = (int*)    alloc((size_t)n * 4);
    int*     bsum   = (int*)    alloc(1024);
    int2*    edge   = (int2*)   alloc((size_t)e * 8 + 256);
    ushort4* xb     = (ushort4*)alloc((size_t)n * 64 * 2);
    ushort4* zbA    = (ushort4*)alloc((size_t)n * 64 * 2);
    ushort4* zbB    = (ushort4*)alloc((size_t)n * 64 * 2);
    float*   g0     = (float*)  alloc((size_t)n * 16 * 4);
    float*   g1     = (float*)  alloc((size_t)n * 16 * 4);
    float*   g2     = (float*)  alloc((size_t)n * 16 * 4);

    hipMemsetAsync(deg, 0, (size_t)n * 4, stream);
    hipMemsetAsync(cnt, 0, (size_t)n * 4, stream);

    int eb = (e + 255) / 256;
    int nb = (n + 255) / 256;

    k_deg    <<<eb, 256, 0, stream>>>(dst, deg, e);
    k_invs   <<<nb, 256, 0, stream>>>(deg, invs, n);
    k_scan1  <<<nb, 256, 0, stream>>>(deg, rowptr, bsum, n);
    k_scan2  <<<1, 256, 0, stream>>>(bsum, nb);
    k_scan3  <<<(n + 256) / 256, 256, 0, stream>>>(rowptr, bsum, n, e);
    k_scatter<<<eb, 256, 0, stream>>>(src, dst, invs, rowptr, cnt, edge, e);

    int total4 = n * 16;
    k_cast<<<(total4 + 255) / 256, 256, 0, stream>>>((const float4*)x, xb, total4);

    int nwaves = COOP_GRID * 256 / 64;
    int nwb = (n + 3) / 4;

    // ---- diffusion loop 1 (bf16, 10 iters) ----
    {
        void* args[] = {(void*)&xb, (void*)&zbA, (void*)&zbB, (void*)&rowptr,
                        (void*)&edge, (void*)&n, (void*)&nwaves};
        hipError_t err = hipLaunchCooperativeKernel((void*)k_diffuse64, dim3(COOP_GRID), dim3(256),
                                                    args, 0, stream);
        if (err != hipSuccess) {
            const ushort4* zin = xb;
            ushort4* zout = zbA;
            for (int it = 0; it < 10; ++it) {
                k_conv64b<<<nwb, 256, 0, stream>>>(zin, xb, zout, rowptr, edge, n);
                zin  = zout;
                zout = (it == 0) ? zbB : ((zout == zbA) ? zbB : zbA);
            }
            // after 10 iters result is in zbB (even# of swaps from zbA start)
        }
    }
    const unsigned short* z1 = (const unsigned short*)zbB;

    int ntiles = (n + 31) / 32;
    k_pairmlp<<<PM_GRID, 256, 0, stream>>>(z1, x, W1, b1, W2, b2,
                                           A1, ab1, A2, ab2, emb, g0, n, ntiles);

    // ---- diffusion loop 2 (fp32, 10 iters, final into d_out) ----
    {
        float4* dout = (float4*)d_out;
        void* args[] = {(void*)&g0, (void*)&g1, (void*)&g2, (void*)&dout,
                        (void*)&rowptr, (void*)&edge, (void*)&n, (void*)&nwaves};
        hipError_t err = hipLaunchCooperativeKernel((void*)k_diffuse16, dim3(COOP_GRID), dim3(256),
                                                    args, 0, stream);
        if (err != hipSuccess) {
            const float* gin = g0;
            float* gout = g1;
            for (int it = 0; it < 10; ++it) {
                float* out = (it == 9) ? (float*)d_out : gout;
                k_conv16<<<nwb, 256, 0, stream>>>((const float4*)gin, (const float4*)g0, (float4*)out,
                                                  rowptr, edge, n);
                gin  = out;
                gout = (gout == g1) ? g2 : g1;
            }
        }
    }
}

// Round 8
// 628.854 us; speedup vs baseline: 5.1075x; 5.1075x over previous
//
#include <hip/hip_runtime.h>

#define FEATS    64
#define CLASSES  16
#define EMB_DIM  7
#define ADJ_HID  11
#define DIFF     0.9f

__device__ inline float bf2f(unsigned short u) {
    return __uint_as_float(((unsigned int)u) << 16);
}
__device__ inline unsigned short f2bf(float f) {
    unsigned int u = __float_as_uint(f);
    return (unsigned short)((u + 0x7FFFu + ((u >> 16) & 1u)) >> 16);
}

// ---------------- graph preprocessing ----------------

__global__ __launch_bounds__(256) void k_deg(const int* __restrict__ dst, int* __restrict__ deg, int e) {
    int i = blockIdx.x * 256 + threadIdx.x;
    if (i < e) atomicAdd(&deg[dst[i]], 1);
}

__global__ __launch_bounds__(256) void k_invs(const int* __restrict__ deg, float* __restrict__ invs, int n) {
    int i = blockIdx.x * 256 + threadIdx.x;
    if (i < n) { int d = deg[i]; invs[i] = d > 0 ? rsqrtf((float)d) : 0.f; }
}

__global__ __launch_bounds__(256) void k_scan1(const int* __restrict__ deg, int* __restrict__ rowptr,
                                               int* __restrict__ bsum, int n) {
    __shared__ int s[256];
    int tid = threadIdx.x;
    int i = blockIdx.x * 256 + tid;
    int v = (i < n) ? deg[i] : 0;
    s[tid] = v; __syncthreads();
    for (int ofs = 1; ofs < 256; ofs <<= 1) {
        int t = (tid >= ofs) ? s[tid - ofs] : 0;
        __syncthreads(); s[tid] += t; __syncthreads();
    }
    if (i < n) rowptr[i] = s[tid] - v;
    if (tid == 255) bsum[blockIdx.x] = s[255];
}

__global__ __launch_bounds__(256) void k_scan2(int* __restrict__ bsum, int nb) {
    __shared__ int s[256];
    int tid = threadIdx.x;
    int v = (tid < nb) ? bsum[tid] : 0;
    s[tid] = v; __syncthreads();
    for (int ofs = 1; ofs < 256; ofs <<= 1) {
        int t = (tid >= ofs) ? s[tid - ofs] : 0;
        __syncthreads(); s[tid] += t; __syncthreads();
    }
    if (tid < nb) bsum[tid] = s[tid] - v;
}

__global__ __launch_bounds__(256) void k_scan3(int* __restrict__ rowptr, const int* __restrict__ bsum,
                                               int n, int e) {
    int i = blockIdx.x * 256 + threadIdx.x;
    if (i < n) rowptr[i] += bsum[i >> 8];
    if (i == n) rowptr[n] = e;
}

__global__ __launch_bounds__(256) void k_scatter(const int* __restrict__ src, const int* __restrict__ dst,
                                                 const float* __restrict__ invs, const int* __restrict__ rowptr,
                                                 int* __restrict__ cnt, int2* __restrict__ edge, int e) {
    int i = blockIdx.x * 256 + threadIdx.x;
    if (i >= e) return;
    int d = dst[i], sv = src[i];
    int pos = rowptr[d] + atomicAdd(&cnt[d], 1);
    edge[pos] = make_int2(sv, __float_as_int(invs[sv] * invs[d]));
}

// ---------------- fp32 -> bf16 cast (x -> xb) ----------------

__global__ __launch_bounds__(256) void k_cast(const float4* __restrict__ in, ushort4* __restrict__ out, int total4) {
    int i = blockIdx.x * 256 + threadIdx.x;
    if (i < total4) {
        float4 v = in[i];
        ushort4 o;
        o.x = f2bf(v.x); o.y = f2bf(v.y); o.z = f2bf(v.z); o.w = f2bf(v.w);
        out[i] = o;
    }
}

// ---------------- conv64 bf16: 1 wave/node, 16 lanes/edge, degree-adaptive prefetch ----------------
// deg<=16: one round (edge-load -> gather chain paid once).
// deg>16 : ALL edge quads for 32 edges loaded up-front into registers, then all
//          gathers issued as edges land -> edge-list latency paid once, not twice.

__global__ __launch_bounds__(256) void k_conv64b(const ushort4* __restrict__ zin, const ushort4* __restrict__ h0b,
                                                 ushort4* __restrict__ zout, const int* __restrict__ rowptr,
                                                 const int2* __restrict__ edge, int n) {
    int wid = (blockIdx.x * 256 + threadIdx.x) >> 6;
    if (wid >= n) return;
    int lane = threadIdx.x & 63;
    int g = lane >> 4, c = lane & 15;
    int e0 = rowptr[wid], e1 = rowptr[wid + 1];
    float a0 = 0.f, a1 = 0.f, a2 = 0.f, a3 = 0.f;

    if (e1 - e0 <= 16) {
        #pragma unroll
        for (int k = 0; k < 4; ++k) {
            int idx = e0 + k * 4 + g;
            bool ok = idx < e1;
            int2 p = edge[ok ? idx : e0];
            float w = ok ? __int_as_float(p.y) : 0.f;
            ushort4 v = zin[(size_t)p.x * 16 + c];
            a0 = fmaf(w, bf2f(v.x), a0);
            a1 = fmaf(w, bf2f(v.y), a1);
            a2 = fmaf(w, bf2f(v.z), a2);
            a3 = fmaf(w, bf2f(v.w), a3);
        }
    } else {
        int2 P[8];
        #pragma unroll
        for (int k = 0; k < 8; ++k) {
            int idx = e0 + k * 4 + g;
            P[k] = edge[idx < e1 ? idx : e0];
        }
        #pragma unroll
        for (int k = 0; k < 8; ++k) {
            int idx = e0 + k * 4 + g;
            float w = (idx < e1) ? __int_as_float(P[k].y) : 0.f;
            ushort4 v = zin[(size_t)P[k].x * 16 + c];
            a0 = fmaf(w, bf2f(v.x), a0);
            a1 = fmaf(w, bf2f(v.y), a1);
            a2 = fmaf(w, bf2f(v.z), a2);
            a3 = fmaf(w, bf2f(v.w), a3);
        }
        for (int e = e0 + 32; e < e1; e += 16) {
            #pragma unroll
            for (int k = 0; k < 4; ++k) {
                int idx = e + k * 4 + g;
                bool ok = idx < e1;
                int2 p = edge[ok ? idx : e0];
                float w = ok ? __int_as_float(p.y) : 0.f;
                ushort4 v = zin[(size_t)p.x * 16 + c];
                a0 = fmaf(w, bf2f(v.x), a0);
                a1 = fmaf(w, bf2f(v.y), a1);
                a2 = fmaf(w, bf2f(v.z), a2);
                a3 = fmaf(w, bf2f(v.w), a3);
            }
        }
    }

    a0 += __shfl_xor(a0, 16); a1 += __shfl_xor(a1, 16);
    a2 += __shfl_xor(a2, 16); a3 += __shfl_xor(a3, 16);
    a0 += __shfl_xor(a0, 32); a1 += __shfl_xor(a1, 32);
    a2 += __shfl_xor(a2, 32); a3 += __shfl_xor(a3, 32);
    if (lane < 16) {
        ushort4 h4 = h0b[(size_t)wid * 16 + lane];
        ushort4 o;
        o.x = f2bf(a0 * DIFF + (1.f - DIFF) * bf2f(h4.x));
        o.y = f2bf(a1 * DIFF + (1.f - DIFF) * bf2f(h4.y));
        o.z = f2bf(a2 * DIFF + (1.f - DIFF) * bf2f(h4.z));
        o.w = f2bf(a3 * DIFF + (1.f - DIFF) * bf2f(h4.w));
        zout[(size_t)wid * 16 + lane] = o;
    }
}

// ---------------- conv16 (fp32, output path): 1 wave/node, 4 lanes/edge ----------------

__global__ __launch_bounds__(256) void k_conv16(const float4* __restrict__ zin4, const float4* __restrict__ g04,
                                                float4* __restrict__ zout4, const int* __restrict__ rowptr,
                                                const int2* __restrict__ edge, int n) {
    int wid = (blockIdx.x * 256 + threadIdx.x) >> 6;
    if (wid >= n) return;
    int lane = threadIdx.x & 63;
    int g = lane >> 2, c = lane & 3;
    int e0 = rowptr[wid], e1 = rowptr[wid + 1];
    float4 acc; acc.x = acc.y = acc.z = acc.w = 0.f;
    for (int e = e0; e < e1; e += 32) {
        #pragma unroll
        for (int k = 0; k < 2; ++k) {
            int idx = e + k * 16 + g;
            bool ok = idx < e1;
            int2 p = edge[ok ? idx : e0];
            float w = ok ? __int_as_float(p.y) : 0.f;
            float4 v = zin4[(size_t)p.x * 4 + c];
            acc.x = fmaf(w, v.x, acc.x);
            acc.y = fmaf(w, v.y, acc.y);
            acc.z = fmaf(w, v.z, acc.z);
            acc.w = fmaf(w, v.w, acc.w);
        }
    }
    #pragma unroll
    for (int m = 4; m <= 32; m <<= 1) {
        acc.x += __shfl_xor(acc.x, m);
        acc.y += __shfl_xor(acc.y, m);
        acc.z += __shfl_xor(acc.z, m);
        acc.w += __shfl_xor(acc.w, m);
    }
    if (lane < 4) {
        float4 h = g04[(size_t)wid * 4 + lane];
        float4 o;
        o.x = acc.x * DIFF + (1.f - DIFF) * h.x;
        o.y = acc.y * DIFF + (1.f - DIFF) * h.y;
        o.z = acc.z * DIFF + (1.f - DIFF) * h.z;
        o.w = acc.w * DIFF + (1.f - DIFF) * h.w;
        zout4[(size_t)wid * 4 + lane] = o;
    }
}

// ---------------- fused pair-MLP + node-MLP, persistent, 16-node tiles ----------------
// LDS ~52.2 KB -> 3 blocks/CU (vs 2 before). PM_GRID = 768.

#define PM_GRID 768

__global__ __launch_bounds__(256) void k_pairmlp(const unsigned short* __restrict__ z1, const float* __restrict__ x,
                                                 const float* __restrict__ W1, const float* __restrict__ b1,
                                                 const float* __restrict__ W2, const float* __restrict__ b2,
                                                 const float* __restrict__ A1, const float* __restrict__ ab1,
                                                 const float* __restrict__ A2, const float* __restrict__ ab2,
                                                 const float* __restrict__ emb,
                                                 float* __restrict__ g0, int n, int ntiles) {
    __shared__ float W1s[128 * 64];          // 32 KB
    __shared__ float W2s[64 * 16];           // 4 KB
    __shared__ float in_s[16][128];          // 8 KB
    __shared__ float hid[16 * 65];           // 4.2 KB
    __shared__ float eA1T[ADJ_HID * 64];     // 2.8 KB
    __shared__ float a0s[ADJ_HID], a1s[ADJ_HID], a2s[ADJ_HID];
    __shared__ float ab2s;

    int tid = threadIdx.x;
    const ushort4* z4p = (const ushort4*)z1;
    const float4*  x4p = (const float4*)x;

    // ---- stage weights once per block ----
    #pragma unroll
    for (int k = 0; k < 32; ++k) W1s[tid + k * 256] = W1[tid + k * 256];
    #pragma unroll
    for (int k = 0; k < 4; ++k)  W2s[tid + k * 256] = W2[tid + k * 256];
    if (tid < ADJ_HID) { a0s[tid] = A1[tid]; a1s[tid] = A1[ADJ_HID + tid]; a2s[tid] = A2[tid]; }
    if (tid == 0) ab2s = ab2[0];
    for (int idx = tid; idx < ADJ_HID * 64; idx += 256) {
        int h = idx >> 6, c = idx & 63;
        float s = ab1[h];
        #pragma unroll
        for (int j = 0; j < EMB_DIM; j++) s = fmaf(emb[c * EMB_DIM + j], A1[(2 + j) * ADJ_HID + h], s);
        eA1T[idx] = s;
    }
    __syncthreads();

    for (int tile = blockIdx.x; tile < ntiles; tile += PM_GRID) {
        int base = tile * 16;

        // ---- phase B: pair MLP, one (node, float4-group) per thread ----
        {
            int nl = tid >> 4, c4 = tid & 15;
            int node = base + nl; if (node > n - 1) node = n - 1;
            ushort4 z4 = z4p[(size_t)node * 16 + c4];
            float4  x4 = x4p[(size_t)node * 16 + c4];
            float zf0 = bf2f(z4.x), zf1 = bf2f(z4.y), zf2 = bf2f(z4.z), zf3 = bf2f(z4.w);
            float o0 = ab2s, o1 = ab2s, o2 = ab2s, o3 = ab2s;
            #pragma unroll
            for (int h = 0; h < ADJ_HID; h++) {
                float a0 = a0s[h], a1 = a1s[h], a2 = a2s[h];
                float4 ee = *(const float4*)&eA1T[h * 64 + c4 * 4];
                float t;
                t = fmaf(zf0, a0, fmaf(x4.x, a1, ee.x)); t = fmaxf(t, 0.f); o0 = fmaf(t, a2, o0);
                t = fmaf(zf1, a0, fmaf(x4.y, a1, ee.y)); t = fmaxf(t, 0.f); o1 = fmaf(t, a2, o1);
                t = fmaf(zf2, a0, fmaf(x4.z, a1, ee.z)); t = fmaxf(t, 0.f); o2 = fmaf(t, a2, o2);
                t = fmaf(zf3, a0, fmaf(x4.w, a1, ee.w)); t = fmaxf(t, 0.f); o3 = fmaf(t, a2, o3);
            }
            *(float4*)&in_s[nl][c4 * 4]      = make_float4(o0 * 0.5f, o1 * 0.5f, o2 * 0.5f, o3 * 0.5f);
            *(float4*)&in_s[nl][64 + c4 * 4] = x4;
        }
        __syncthreads();

        // ---- phase C: GEMM1, wave wv handles nodes wv*4..wv*4+3, lane = hidden unit ----
        {
            int lane = tid & 63, wv = tid >> 6;
            int nb0 = wv * 4;
            float bv = b1[lane];
            float acc[4];
            #pragma unroll
            for (int j = 0; j < 4; ++j) acc[j] = bv;
            #pragma unroll 8
            for (int rb = 0; rb < 128; rb += 4) {
                float w0 = W1s[(rb    ) * 64 + lane];
                float w1 = W1s[(rb + 1) * 64 + lane];
                float w2 = W1s[(rb + 2) * 64 + lane];
                float w3 = W1s[(rb + 3) * 64 + lane];
                #pragma unroll
                for (int j = 0; j < 4; ++j) {
                    float4 iv = *(const float4*)&in_s[nb0 + j][rb];
                    acc[j] = fmaf(iv.w, w3, fmaf(iv.z, w2, fmaf(iv.y, w1, fmaf(iv.x, w0, acc[j]))));
                }
            }
            #pragma unroll
            for (int j = 0; j < 4; ++j) hid[(nb0 + j) * 65 + lane] = fmaxf(acc[j], 0.f);
        }
        __syncthreads();

        // ---- phase D: GEMM2, one (node, class) per thread ----
        {
            int c  = tid & 15;
            int nl = tid >> 4;
            float ac = b2[c];
            #pragma unroll
            for (int h = 0; h < 64; ++h)
                ac = fmaf(hid[nl * 65 + h], W2s[h * 16 + c], ac);
            int n0 = base + nl;
            if (n0 < n) g0[(size_t)n0 * 16 + c] = ac;
        }
        __syncthreads();
    }
}

// ---------------- launch ----------------

extern "C" void kernel_launch(void* const* d_in, const int* in_sizes, int n_in,
                              void* d_out, int out_size, void* d_ws, size_t ws_size,
                              hipStream_t stream) {
    const float* x   = (const float*)d_in[0];
    const int*   src = (const int*)d_in[1];
    const int*   dst = (const int*)d_in[2];
    const float* W1  = (const float*)d_in[3];
    const float* b1  = (const float*)d_in[4];
    const float* W2  = (const float*)d_in[5];
    const float* b2  = (const float*)d_in[6];
    const float* A1  = (const float*)d_in[7];
    const float* ab1 = (const float*)d_in[8];
    const float* A2  = (const float*)d_in[9];
    const float* ab2 = (const float*)d_in[10];
    const float* emb = (const float*)d_in[11];

    int n = in_sizes[0] / FEATS;   // 50000
    int e = in_sizes[1];           // 800000

    char* ws = (char*)d_ws;
    size_t off = 0;
    auto alloc = [&](size_t bytes) {
        void* p = ws + off;
        off += bytes;
        off = (off + 255) & ~(size_t)255;
        return p;
    };

    int*     deg    = (int*)    alloc((size_t)n * 4);
    float*   invs   = (float*)  alloc((size_t)n * 4);
    int*     rowptr = (int*)    alloc((size_t)(n + 1) * 4);
    int*     cnt    = (int*)    alloc((size_t)n * 4);
    int*     bsum   = (int*)    alloc(1024);
    int2*    edge   = (int2*)   alloc((size_t)e * 8 + 256);
    ushort4* xb     = (ushort4*)alloc((size_t)n * 64 * 2);
    ushort4* zbA    = (ushort4*)alloc((size_t)n * 64 * 2);
    ushort4* zbB    = (ushort4*)alloc((size_t)n * 64 * 2);
    float*   g0     = (float*)  alloc((size_t)n * 16 * 4);
    float*   g1     = (float*)  alloc((size_t)n * 16 * 4);
    float*   g2     = (float*)  alloc((size_t)n * 16 * 4);

    hipMemsetAsync(deg, 0, (size_t)n * 4, stream);
    hipMemsetAsync(cnt, 0, (size_t)n * 4, stream);

    int eb = (e + 255) / 256;
    int nb = (n + 255) / 256;

    k_deg    <<<eb, 256, 0, stream>>>(dst, deg, e);
    k_invs   <<<nb, 256, 0, stream>>>(deg, invs, n);
    k_scan1  <<<nb, 256, 0, stream>>>(deg, rowptr, bsum, n);
    k_scan2  <<<1, 256, 0, stream>>>(bsum, nb);
    k_scan3  <<<(n + 256) / 256, 256, 0, stream>>>(rowptr, bsum, n, e);
    k_scatter<<<eb, 256, 0, stream>>>(src, dst, invs, rowptr, cnt, edge, e);

    int total4 = n * 16;
    k_cast<<<(total4 + 255) / 256, 256, 0, stream>>>((const float4*)x, xb, total4);

    int nwb = (n + 3) / 4;   // 4 waves (nodes) per 256-thread block

    // ---- diffusion loop 1 (bf16, 10 iters) ----
    const ushort4* zin = xb;
    ushort4* zout = zbA;
    for (int it = 0; it < 10; ++it) {
        k_conv64b<<<nwb, 256, 0, stream>>>(zin, xb, zout, rowptr, edge, n);
        zin  = zout;
        zout = (it == 0) ? zbB : ((zout == zbA) ? zbB : zbA);
    }
    const unsigned short* z1 = (const unsigned short*)zin;

    int ntiles = (n + 15) / 16;
    k_pairmlp<<<PM_GRID, 256, 0, stream>>>(z1, x, W1, b1, W2, b2,
                                           A1, ab1, A2, ab2, emb, g0, n, ntiles);

    // ---- diffusion loop 2 (fp32, 10 iters) ----
    const float* gin = g0;
    float* gout = g1;
    for (int it = 0; it < 10; ++it) {
        float* out = (it == 9) ? (float*)d_out : gout;
        k_conv16<<<nwb, 256, 0, stream>>>((const float4*)gin, (const float4*)g0, (float4*)out,
                                          rowptr, edge, n);
        gin  = out;
        gout = (gout == g1) ? g2 : g1;
    }
}

// Round 13
// 626.371 us; speedup vs baseline: 5.1277x; 1.0040x over previous
//
#include <hip/hip_runtime.h>

#define FEATS    64
#define CLASSES  16
#define EMB_DIM  7
#define ADJ_HID  11
#define DIFF     0.9f

__device__ inline float bf2f(unsigned short u) {
    return __uint_as_float(((unsigned int)u) << 16);
}
__device__ inline unsigned short f2bf(float f) {
    unsigned int u = __float_as_uint(f);
    return (unsigned short)((u + 0x7FFFu + ((u >> 16) & 1u)) >> 16);
}

// ---------------- graph preprocessing ----------------

__global__ __launch_bounds__(256) void k_deg(const int* __restrict__ dst, int* __restrict__ deg, int e) {
    int i = blockIdx.x * 256 + threadIdx.x;
    if (i < e) atomicAdd(&deg[dst[i]], 1);
}

__global__ __launch_bounds__(256) void k_invs(const int* __restrict__ deg, float* __restrict__ invs, int n) {
    int i = blockIdx.x * 256 + threadIdx.x;
    if (i < n) { int d = deg[i]; invs[i] = d > 0 ? rsqrtf((float)d) : 0.f; }
}

__global__ __launch_bounds__(256) void k_scan1(const int* __restrict__ deg, int* __restrict__ rowptr,
                                               int* __restrict__ bsum, int n) {
    __shared__ int s[256];
    int tid = threadIdx.x;
    int i = blockIdx.x * 256 + tid;
    int v = (i < n) ? deg[i] : 0;
    s[tid] = v; __syncthreads();
    for (int ofs = 1; ofs < 256; ofs <<= 1) {
        int t = (tid >= ofs) ? s[tid - ofs] : 0;
        __syncthreads(); s[tid] += t; __syncthreads();
    }
    if (i < n) rowptr[i] = s[tid] - v;
    if (tid == 255) bsum[blockIdx.x] = s[255];
}

__global__ __launch_bounds__(256) void k_scan2(int* __restrict__ bsum, int nb) {
    __shared__ int s[256];
    int tid = threadIdx.x;
    int v = (tid < nb) ? bsum[tid] : 0;
    s[tid] = v; __syncthreads();
    for (int ofs = 1; ofs < 256; ofs <<= 1) {
        int t = (tid >= ofs) ? s[tid - ofs] : 0;
        __syncthreads(); s[tid] += t; __syncthreads();
    }
    if (tid < nb) bsum[tid] = s[tid] - v;
}

__global__ __launch_bounds__(256) void k_scan3(int* __restrict__ rowptr, const int* __restrict__ bsum,
                                               int n, int e) {
    int i = blockIdx.x * 256 + threadIdx.x;
    if (i < n) rowptr[i] += bsum[i >> 8];
    if (i == n) rowptr[n] = e;
}

__global__ __launch_bounds__(256) void k_scatter(const int* __restrict__ src, const int* __restrict__ dst,
                                                 const float* __restrict__ invs, const int* __restrict__ rowptr,
                                                 int* __restrict__ cnt, int2* __restrict__ edge, int e) {
    int i = blockIdx.x * 256 + threadIdx.x;
    if (i >= e) return;
    int d = dst[i], sv = src[i];
    int pos = rowptr[d] + atomicAdd(&cnt[d], 1);
    edge[pos] = make_int2(sv, __float_as_int(invs[sv] * invs[d]));
}

// ---------------- fp32 -> bf16 cast (x -> xb) ----------------

__global__ __launch_bounds__(256) void k_cast(const float4* __restrict__ in, ushort4* __restrict__ out, int total4) {
    int i = blockIdx.x * 256 + threadIdx.x;
    if (i < total4) {
        float4 v = in[i];
        ushort4 o;
        o.x = f2bf(v.x); o.y = f2bf(v.y); o.z = f2bf(v.z); o.w = f2bf(v.w);
        out[i] = o;
    }
}

// ---------------- conv64 bf16: 1 wave per 4 consecutive nodes ----------------
// Round: ONE coalesced 64-edge load (8B/lane) -> shfl-broadcast -> 16
// independent 4-edge row-gathers issued back-to-back (~8KB in flight/wave)
// -> per-node predicated accumulate -> butterfly reduce -> coalesced store.

__global__ __launch_bounds__(256) void k_conv64b(const ushort4* __restrict__ zin, const ushort4* __restrict__ h0b,
                                                 ushort4* __restrict__ zout, const int* __restrict__ rowptr,
                                                 const int2* __restrict__ edge, int n) {
    int wq = (blockIdx.x * 256 + threadIdx.x) >> 6;   // node-quad id
    int n0 = wq * 4;
    if (n0 >= n) return;
    int lane = threadIdx.x & 63;
    int g = lane >> 4, c = lane & 15;

    // rowptr boundaries r0..r4 (clamped for tail quads)
    int v = 0;
    if (lane < 5) v = rowptr[min(n0 + lane, n)];
    int r0 = __shfl(v, 0), r1 = __shfl(v, 1), r2 = __shfl(v, 2),
        r3 = __shfl(v, 3), r4 = __shfl(v, 4);

    // independent: prefetch h0 row for own node (n0+g)
    ushort4 h4 = make_ushort4(0, 0, 0, 0);
    if (n0 + g < n) h4 = h0b[(size_t)(n0 + g) * 16 + c];

    float a[4][4];
    #pragma unroll
    for (int j = 0; j < 4; ++j)
        #pragma unroll
        for (int f = 0; f < 4; ++f) a[j][f] = 0.f;

    for (int eb = r0; eb < r4; eb += 64) {
        int2 pe = edge[min(eb + lane, r4 - 1)];
        int   es = pe.x;
        float ew = __int_as_float(pe.y);
        #pragma unroll
        for (int k = 0; k < 16; ++k) {
            int s   = k * 4 + g;
            int idx = eb + s;
            int   srcn = __shfl(es, s);
            float wraw = __shfl(ew, s);
            float w = (idx < r4) ? wraw : 0.f;
            int nid = (idx >= r1) + (idx >= r2) + (idx >= r3);
            ushort4 vv = zin[(size_t)srcn * 16 + c];
            float f0 = bf2f(vv.x), f1 = bf2f(vv.y), f2 = bf2f(vv.z), f3 = bf2f(vv.w);
            #pragma unroll
            for (int j = 0; j < 4; ++j) {
                float sel = (nid == j) ? w : 0.f;
                a[j][0] = fmaf(sel, f0, a[j][0]);
                a[j][1] = fmaf(sel, f1, a[j][1]);
                a[j][2] = fmaf(sel, f2, a[j][2]);
                a[j][3] = fmaf(sel, f3, a[j][3]);
            }
        }
    }

    // butterfly over the 4 groups (bits 4,5)
    #pragma unroll
    for (int j = 0; j < 4; ++j) {
        #pragma unroll
        for (int f = 0; f < 4; ++f) {
            a[j][f] += __shfl_xor(a[j][f], 16);
            a[j][f] += __shfl_xor(a[j][f], 32);
        }
    }

    // lane (g,c) writes node n0+g, ushort4 slot c
    if (n0 + g < n) {
        float o0 = (g == 0) ? a[0][0] : (g == 1) ? a[1][0] : (g == 2) ? a[2][0] : a[3][0];
        float o1 = (g == 0) ? a[0][1] : (g == 1) ? a[1][1] : (g == 2) ? a[2][1] : a[3][1];
        float o2 = (g == 0) ? a[0][2] : (g == 1) ? a[1][2] : (g == 2) ? a[2][2] : a[3][2];
        float o3 = (g == 0) ? a[0][3] : (g == 1) ? a[1][3] : (g == 2) ? a[2][3] : a[3][3];
        ushort4 o;
        o.x = f2bf(o0 * DIFF + (1.f - DIFF) * bf2f(h4.x));
        o.y = f2bf(o1 * DIFF + (1.f - DIFF) * bf2f(h4.y));
        o.z = f2bf(o2 * DIFF + (1.f - DIFF) * bf2f(h4.z));
        o.w = f2bf(o3 * DIFF + (1.f - DIFF) * bf2f(h4.w));
        zout[(size_t)(n0 + g) * 16 + c] = o;
    }
}

// ---------------- conv16 fp32: 1 wave per 4 consecutive nodes ----------------
// Same template; 16 groups of 4 lanes (float4/lane), 4 sub-rounds of 16 edges.

__global__ __launch_bounds__(256) void k_conv16(const float4* __restrict__ zin4, const float4* __restrict__ g04,
                                                float4* __restrict__ zout4, const int* __restrict__ rowptr,
                                                const int2* __restrict__ edge, int n) {
    int wq = (blockIdx.x * 256 + threadIdx.x) >> 6;
    int n0 = wq * 4;
    if (n0 >= n) return;
    int lane = threadIdx.x & 63;
    int g = lane >> 2, c = lane & 3;   // g: 0..15

    int v = 0;
    if (lane < 5) v = rowptr[min(n0 + lane, n)];
    int r0 = __shfl(v, 0), r1 = __shfl(v, 1), r2 = __shfl(v, 2),
        r3 = __shfl(v, 3), r4 = __shfl(v, 4);

    float4 h = make_float4(0.f, 0.f, 0.f, 0.f);
    if (g < 4 && n0 + g < n) h = g04[(size_t)(n0 + g) * 4 + c];

    float a[4][4];
    #pragma unroll
    for (int j = 0; j < 4; ++j)
        #pragma unroll
        for (int f = 0; f < 4; ++f) a[j][f] = 0.f;

    for (int eb = r0; eb < r4; eb += 64) {
        int2 pe = edge[min(eb + lane, r4 - 1)];
        int   es = pe.x;
        float ew = __int_as_float(pe.y);
        #pragma unroll
        for (int k = 0; k < 4; ++k) {
            int s   = k * 16 + g;
            int idx = eb + s;
            int   srcn = __shfl(es, s);
            float wraw = __shfl(ew, s);
            float w = (idx < r4) ? wraw : 0.f;
            int nid = (idx >= r1) + (idx >= r2) + (idx >= r3);
            float4 vv = zin4[(size_t)srcn * 4 + c];
            #pragma unroll
            for (int j = 0; j < 4; ++j) {
                float sel = (nid == j) ? w : 0.f;
                a[j][0] = fmaf(sel, vv.x, a[j][0]);
                a[j][1] = fmaf(sel, vv.y, a[j][1]);
                a[j][2] = fmaf(sel, vv.z, a[j][2]);
                a[j][3] = fmaf(sel, vv.w, a[j][3]);
            }
        }
    }

    // butterfly over 16 groups (bits 2..5)
    #pragma unroll
    for (int j = 0; j < 4; ++j) {
        #pragma unroll
        for (int f = 0; f < 4; ++f) {
            a[j][f] += __shfl_xor(a[j][f], 4);
            a[j][f] += __shfl_xor(a[j][f], 8);
            a[j][f] += __shfl_xor(a[j][f], 16);
            a[j][f] += __shfl_xor(a[j][f], 32);
        }
    }

    if (g < 4 && n0 + g < n) {
        float o0 = (g == 0) ? a[0][0] : (g == 1) ? a[1][0] : (g == 2) ? a[2][0] : a[3][0];
        float o1 = (g == 0) ? a[0][1] : (g == 1) ? a[1][1] : (g == 2) ? a[2][1] : a[3][1];
        float o2 = (g == 0) ? a[0][2] : (g == 1) ? a[1][2] : (g == 2) ? a[2][2] : a[3][2];
        float o3 = (g == 0) ? a[0][3] : (g == 1) ? a[1][3] : (g == 2) ? a[2][3] : a[3][3];
        float4 o;
        o.x = o0 * DIFF + (1.f - DIFF) * h.x;
        o.y = o1 * DIFF + (1.f - DIFF) * h.y;
        o.z = o2 * DIFF + (1.f - DIFF) * h.z;
        o.w = o3 * DIFF + (1.f - DIFF) * h.w;
        zout4[(size_t)(n0 + g) * 4 + c] = o;
    }
}

// ---------------- fused pair-MLP + node-MLP, persistent, 16-node tiles ----------------

#define PM_GRID 768

__global__ __launch_bounds__(256) void k_pairmlp(const unsigned short* __restrict__ z1, const float* __restrict__ x,
                                                 const float* __restrict__ W1, const float* __restrict__ b1,
                                                 const float* __restrict__ W2, const float* __restrict__ b2,
                                                 const float* __restrict__ A1, const float* __restrict__ ab1,
                                                 const float* __restrict__ A2, const float* __restrict__ ab2,
                                                 const float* __restrict__ emb,
                                                 float* __restrict__ g0, int n, int ntiles) {
    __shared__ float W1s[128 * 64];
    __shared__ float W2s[64 * 16];
    __shared__ float in_s[16][128];
    __shared__ float hid[16 * 65];
    __shared__ float eA1T[ADJ_HID * 64];
    __shared__ float a0s[ADJ_HID], a1s[ADJ_HID], a2s[ADJ_HID];
    __shared__ float ab2s;

    int tid = threadIdx.x;
    const ushort4* z4p = (const ushort4*)z1;
    const float4*  x4p = (const float4*)x;

    #pragma unroll
    for (int k = 0; k < 32; ++k) W1s[tid + k * 256] = W1[tid + k * 256];
    #pragma unroll
    for (int k = 0; k < 4; ++k)  W2s[tid + k * 256] = W2[tid + k * 256];
    if (tid < ADJ_HID) { a0s[tid] = A1[tid]; a1s[tid] = A1[ADJ_HID + tid]; a2s[tid] = A2[tid]; }
    if (tid == 0) ab2s = ab2[0];
    for (int idx = tid; idx < ADJ_HID * 64; idx += 256) {
        int h = idx >> 6, c = idx & 63;
        float s = ab1[h];
        #pragma unroll
        for (int j = 0; j < EMB_DIM; j++) s = fmaf(emb[c * EMB_DIM + j], A1[(2 + j) * ADJ_HID + h], s);
        eA1T[idx] = s;
    }
    __syncthreads();

    for (int tile = blockIdx.x; tile < ntiles; tile += PM_GRID) {
        int base = tile * 16;

        {
            int nl = tid >> 4, c4 = tid & 15;
            int node = base + nl; if (node > n - 1) node = n - 1;
            ushort4 z4 = z4p[(size_t)node * 16 + c4];
            float4  x4 = x4p[(size_t)node * 16 + c4];
            float zf0 = bf2f(z4.x), zf1 = bf2f(z4.y), zf2 = bf2f(z4.z), zf3 = bf2f(z4.w);
            float o0 = ab2s, o1 = ab2s, o2 = ab2s, o3 = ab2s;
            #pragma unroll
            for (int h = 0; h < ADJ_HID; h++) {
                float a0 = a0s[h], a1 = a1s[h], a2 = a2s[h];
                float4 ee = *(const float4*)&eA1T[h * 64 + c4 * 4];
                float t;
                t = fmaf(zf0, a0, fmaf(x4.x, a1, ee.x)); t = fmaxf(t, 0.f); o0 = fmaf(t, a2, o0);
                t = fmaf(zf1, a0, fmaf(x4.y, a1, ee.y)); t = fmaxf(t, 0.f); o1 = fmaf(t, a2, o1);
                t = fmaf(zf2, a0, fmaf(x4.z, a1, ee.z)); t = fmaxf(t, 0.f); o2 = fmaf(t, a2, o2);
                t = fmaf(zf3, a0, fmaf(x4.w, a1, ee.w)); t = fmaxf(t, 0.f); o3 = fmaf(t, a2, o3);
            }
            *(float4*)&in_s[nl][c4 * 4]      = make_float4(o0 * 0.5f, o1 * 0.5f, o2 * 0.5f, o3 * 0.5f);
            *(float4*)&in_s[nl][64 + c4 * 4] = x4;
        }
        __syncthreads();

        {
            int lane = tid & 63, wv = tid >> 6;
            int nb0 = wv * 4;
            float bv = b1[lane];
            float acc[4];
            #pragma unroll
            for (int j = 0; j < 4; ++j) acc[j] = bv;
            #pragma unroll 8
            for (int rb = 0; rb < 128; rb += 4) {
                float w0 = W1s[(rb    ) * 64 + lane];
                float w1 = W1s[(rb + 1) * 64 + lane];
                float w2 = W1s[(rb + 2) * 64 + lane];
                float w3 = W1s[(rb + 3) * 64 + lane];
                #pragma unroll
                for (int j = 0; j < 4; ++j) {
                    float4 iv = *(const float4*)&in_s[nb0 + j][rb];
                    acc[j] = fmaf(iv.w, w3, fmaf(iv.z, w2, fmaf(iv.y, w1, fmaf(iv.x, w0, acc[j]))));
                }
            }
            #pragma unroll
            for (int j = 0; j < 4; ++j) hid[(nb0 + j) * 65 + lane] = fmaxf(acc[j], 0.f);
        }
        __syncthreads();

        {
            int c  = tid & 15;
            int nl = tid >> 4;
            float ac = b2[c];
            #pragma unroll
            for (int h = 0; h < 64; ++h)
                ac = fmaf(hid[nl * 65 + h], W2s[h * 16 + c], ac);
            int n0 = base + nl;
            if (n0 < n) g0[(size_t)n0 * 16 + c] = ac;
        }
        __syncthreads();
    }
}

// ---------------- launch ----------------

extern "C" void kernel_launch(void* const* d_in, const int* in_sizes, int n_in,
                              void* d_out, int out_size, void* d_ws, size_t ws_size,
                              hipStream_t stream) {
    const float* x   = (const float*)d_in[0];
    const int*   src = (const int*)d_in[1];
    const int*   dst = (const int*)d_in[2];
    const float* W1  = (const float*)d_in[3];
    const float* b1  = (const float*)d_in[4];
    const float* W2  = (const float*)d_in[5];
    const float* b2  = (const float*)d_in[6];
    const float* A1  = (const float*)d_in[7];
    const float* ab1 = (const float*)d_in[8];
    const float* A2  = (const float*)d_in[9];
    const float* ab2 = (const float*)d_in[10];
    const float* emb = (const float*)d_in[11];

    int n = in_sizes[0] / FEATS;   // 50000
    int e = in_sizes[1];           // 800000

    char* ws = (char*)d_ws;
    size_t off = 0;
    auto alloc = [&](size_t bytes) {
        void* p = ws + off;
        off += bytes;
        off = (off + 255) & ~(size_t)255;
        return p;
    };

    int*     deg    = (int*)    alloc((size_t)n * 4);
    float*   invs   = (float*)  alloc((size_t)n * 4);
    int*     rowptr = (int*)    alloc((size_t)(n + 1) * 4);
    int*     cnt    = (int*)    alloc((size_t)n * 4);
    int*     bsum   = (int*)    alloc(1024);
    int2*    edge   = (int2*)   alloc((size_t)e * 8 + 256);
    ushort4* xb     = (ushort4*)alloc((size_t)n * 64 * 2);
    ushort4* zbA    = (ushort4*)alloc((size_t)n * 64 * 2);
    ushort4* zbB    = (ushort4*)alloc((size_t)n * 64 * 2);
    float*   g0     = (float*)  alloc((size_t)n * 16 * 4);
    float*   g1     = (float*)  alloc((size_t)n * 16 * 4);
    float*   g2     = (float*)  alloc((size_t)n * 16 * 4);

    hipMemsetAsync(deg, 0, (size_t)n * 4, stream);
    hipMemsetAsync(cnt, 0, (size_t)n * 4, stream);

    int eb = (e + 255) / 256;
    int nb = (n + 255) / 256;

    k_deg    <<<eb, 256, 0, stream>>>(dst, deg, e);
    k_invs   <<<nb, 256, 0, stream>>>(deg, invs, n);
    k_scan1  <<<nb, 256, 0, stream>>>(deg, rowptr, bsum, n);
    k_scan2  <<<1, 256, 0, stream>>>(bsum, nb);
    k_scan3  <<<(n + 256) / 256, 256, 0, stream>>>(rowptr, bsum, n, e);
    k_scatter<<<eb, 256, 0, stream>>>(src, dst, invs, rowptr, cnt, edge, e);

    int total4 = n * 16;
    k_cast<<<(total4 + 255) / 256, 256, 0, stream>>>((const float4*)x, xb, total4);

    int nquad = (n + 3) / 4;
    int cblocks = (nquad + 3) / 4;   // 4 waves (node-quads) per 256-thread block

    // ---- diffusion loop 1 (bf16, 10 iters) ----
    const ushort4* zin = xb;
    ushort4* zout = zbA;
    for (int it = 0; it < 10; ++it) {
        k_conv64b<<<cblocks, 256, 0, stream>>>(zin, xb, zout, rowptr, edge, n);
        zin  = zout;
        zout = (it == 0) ? zbB : ((zout == zbA) ? zbB : zbA);
    }
    const unsigned short* z1 = (const unsigned short*)zin;

    int ntiles = (n + 15) / 16;
    k_pairmlp<<<PM_GRID, 256, 0, stream>>>(z1, x, W1, b1, W2, b2,
                                           A1, ab1, A2, ab2, emb, g0, n, ntiles);

    // ---- diffusion loop 2 (fp32, 10 iters) ----
    const float* gin = g0;
    float* gout = g1;
    for (int it = 0; it < 10; ++it) {
        float* out = (it == 9) ? (float*)d_out : gout;
        k_conv16<<<cblocks, 256, 0, stream>>>((const float4*)gin, (const float4*)g0, (float4*)out,
                                              rowptr, edge, n);
        gin  = out;
        gout = (gout == g1) ? g2 : g1;
    }
}

// Round 17
// 614.376 us; speedup vs baseline: 5.2278x; 1.0195x over previous
//
#include <hip/hip_runtime.h>
#include <hip/hip_fp16.h>

#define FEATS    64
#define CLASSES  16
#define EMB_DIM  7
#define ADJ_HID  11
#define DIFF     0.9f

__device__ inline float bf2f(unsigned short u) {
    return __uint_as_float(((unsigned int)u) << 16);
}
__device__ inline unsigned short f2bf(float f) {
    unsigned int u = __float_as_uint(f);
    return (unsigned short)((u + 0x7FFFu + ((u >> 16) & 1u)) >> 16);
}
__device__ inline float edge_w(unsigned int u) {
    return __half2float(__ushort_as_half((unsigned short)(u & 0xFFFFu)));
}

// ---------------- graph preprocessing ----------------

__global__ __launch_bounds__(256) void k_deg(const int* __restrict__ dst, int* __restrict__ deg, int e) {
    int i = blockIdx.x * 256 + threadIdx.x;
    if (i < e) atomicAdd(&deg[dst[i]], 1);
}

__global__ __launch_bounds__(256) void k_invs(const int* __restrict__ deg, float* __restrict__ invs, int n) {
    int i = blockIdx.x * 256 + threadIdx.x;
    if (i < n) { int d = deg[i]; invs[i] = d > 0 ? rsqrtf((float)d) : 0.f; }
}

__global__ __launch_bounds__(256) void k_scan1(const int* __restrict__ deg, int* __restrict__ rowptr,
                                               int* __restrict__ bsum, int n) {
    __shared__ int s[256];
    int tid = threadIdx.x;
    int i = blockIdx.x * 256 + tid;
    int v = (i < n) ? deg[i] : 0;
    s[tid] = v; __syncthreads();
    for (int ofs = 1; ofs < 256; ofs <<= 1) {
        int t = (tid >= ofs) ? s[tid - ofs] : 0;
        __syncthreads(); s[tid] += t; __syncthreads();
    }
    if (i < n) rowptr[i] = s[tid] - v;
    if (tid == 255) bsum[blockIdx.x] = s[255];
}

__global__ __launch_bounds__(256) void k_scan2(int* __restrict__ bsum, int nb) {
    __shared__ int s[256];
    int tid = threadIdx.x;
    int v = (tid < nb) ? bsum[tid] : 0;
    s[tid] = v; __syncthreads();
    for (int ofs = 1; ofs < 256; ofs <<= 1) {
        int t = (tid >= ofs) ? s[tid - ofs] : 0;
        __syncthreads(); s[tid] += t; __syncthreads();
    }
    if (tid < nb) bsum[tid] = s[tid] - v;
}

__global__ __launch_bounds__(256) void k_scan3(int* __restrict__ rowptr, const int* __restrict__ bsum,
                                               int n, int e) {
    int i = blockIdx.x * 256 + threadIdx.x;
    if (i < n) rowptr[i] += bsum[i >> 8];
    if (i == n) rowptr[n] = e;
}

// XCD-range-partitioned scatter: group g (blockIdx&7) writes only dst in
// [g*n/8,(g+1)*n/8) -> each CSR output range dirtied by ~one XCD's L2.
// Edge packed to 4B: (src:16 | fp16(norm):16).
__global__ __launch_bounds__(256) void k_scatter(const int* __restrict__ src, const int* __restrict__ dst,
                                                 const float* __restrict__ invs, const int* __restrict__ rowptr,
                                                 int* __restrict__ cnt, unsigned int* __restrict__ edge,
                                                 int e, int n) {
    int grp = blockIdx.x & 7;
    int lo = (int)(((long long)n * grp) >> 3);
    int hi = (int)(((long long)n * (grp + 1)) >> 3);
    int stride = (gridDim.x >> 3) * 256;
    for (int i = (blockIdx.x >> 3) * 256 + threadIdx.x; i < e; i += stride) {
        int d = dst[i];
        if (d < lo || d >= hi) continue;
        int sv = src[i];
        int pos = rowptr[d] + atomicAdd(&cnt[d], 1);
        float nm = invs[sv] * invs[d];
        unsigned short hb = __half_as_ushort(__float2half(nm));
        edge[pos] = ((unsigned int)sv << 16) | (unsigned int)hb;
    }
}

// ---------------- fp32 -> bf16 cast (x -> xb) ----------------

__global__ __launch_bounds__(256) void k_cast(const float4* __restrict__ in, ushort4* __restrict__ out, int total4) {
    int i = blockIdx.x * 256 + threadIdx.x;
    if (i < total4) {
        float4 v = in[i];
        ushort4 o;
        o.x = f2bf(v.x); o.y = f2bf(v.y); o.z = f2bf(v.z); o.w = f2bf(v.w);
        out[i] = o;
    }
}

// ---------------- conv64 bf16: 1 wave per 4 consecutive nodes ----------------

__global__ __launch_bounds__(256) void k_conv64b(const ushort4* __restrict__ zin, const ushort4* __restrict__ h0b,
                                                 ushort4* __restrict__ zout, const int* __restrict__ rowptr,
                                                 const unsigned int* __restrict__ edge, int n) {
    int wq = (blockIdx.x * 256 + threadIdx.x) >> 6;   // node-quad id
    int n0 = wq * 4;
    if (n0 >= n) return;
    int lane = threadIdx.x & 63;
    int g = lane >> 4, c = lane & 15;

    int v = 0;
    if (lane < 5) v = rowptr[min(n0 + lane, n)];
    int r0 = __shfl(v, 0), r1 = __shfl(v, 1), r2 = __shfl(v, 2),
        r3 = __shfl(v, 3), r4 = __shfl(v, 4);

    ushort4 h4 = make_ushort4(0, 0, 0, 0);
    if (n0 + g < n) h4 = h0b[(size_t)(n0 + g) * 16 + c];

    float a[4][4];
    #pragma unroll
    for (int j = 0; j < 4; ++j)
        #pragma unroll
        for (int f = 0; f < 4; ++f) a[j][f] = 0.f;

    for (int eb = r0; eb < r4; eb += 64) {
        unsigned int pe = edge[min(eb + lane, r4 - 1)];
        #pragma unroll
        for (int k = 0; k < 16; ++k) {
            int s   = k * 4 + g;
            int idx = eb + s;
            unsigned int ue = __shfl(pe, s);
            int   srcn = (int)(ue >> 16);
            float w = (idx < r4) ? edge_w(ue) : 0.f;
            int nid = (idx >= r1) + (idx >= r2) + (idx >= r3);
            ushort4 vv = zin[(size_t)srcn * 16 + c];
            float f0 = bf2f(vv.x), f1 = bf2f(vv.y), f2 = bf2f(vv.z), f3 = bf2f(vv.w);
            #pragma unroll
            for (int j = 0; j < 4; ++j) {
                float sel = (nid == j) ? w : 0.f;
                a[j][0] = fmaf(sel, f0, a[j][0]);
                a[j][1] = fmaf(sel, f1, a[j][1]);
                a[j][2] = fmaf(sel, f2, a[j][2]);
                a[j][3] = fmaf(sel, f3, a[j][3]);
            }
        }
    }

    #pragma unroll
    for (int j = 0; j < 4; ++j) {
        #pragma unroll
        for (int f = 0; f < 4; ++f) {
            a[j][f] += __shfl_xor(a[j][f], 16);
            a[j][f] += __shfl_xor(a[j][f], 32);
        }
    }

    if (n0 + g < n) {
        float o0 = (g == 0) ? a[0][0] : (g == 1) ? a[1][0] : (g == 2) ? a[2][0] : a[3][0];
        float o1 = (g == 0) ? a[0][1] : (g == 1) ? a[1][1] : (g == 2) ? a[2][1] : a[3][1];
        float o2 = (g == 0) ? a[0][2] : (g == 1) ? a[1][2] : (g == 2) ? a[2][2] : a[3][2];
        float o3 = (g == 0) ? a[0][3] : (g == 1) ? a[1][3] : (g == 2) ? a[2][3] : a[3][3];
        ushort4 o;
        o.x = f2bf(o0 * DIFF + (1.f - DIFF) * bf2f(h4.x));
        o.y = f2bf(o1 * DIFF + (1.f - DIFF) * bf2f(h4.y));
        o.z = f2bf(o2 * DIFF + (1.f - DIFF) * bf2f(h4.z));
        o.w = f2bf(o3 * DIFF + (1.f - DIFF) * bf2f(h4.w));
        zout[(size_t)(n0 + g) * 16 + c] = o;
    }
}

// ---------------- conv16 fp32: 1 wave per 4 consecutive nodes ----------------

__global__ __launch_bounds__(256) void k_conv16(const float4* __restrict__ zin4, const float4* __restrict__ g04,
                                                float4* __restrict__ zout4, const int* __restrict__ rowptr,
                                                const unsigned int* __restrict__ edge, int n) {
    int wq = (blockIdx.x * 256 + threadIdx.x) >> 6;
    int n0 = wq * 4;
    if (n0 >= n) return;
    int lane = threadIdx.x & 63;
    int g = lane >> 2, c = lane & 3;   // g: 0..15

    int v = 0;
    if (lane < 5) v = rowptr[min(n0 + lane, n)];
    int r0 = __shfl(v, 0), r1 = __shfl(v, 1), r2 = __shfl(v, 2),
        r3 = __shfl(v, 3), r4 = __shfl(v, 4);

    float4 h = make_float4(0.f, 0.f, 0.f, 0.f);
    if (g < 4 && n0 + g < n) h = g04[(size_t)(n0 + g) * 4 + c];

    float a[4][4];
    #pragma unroll
    for (int j = 0; j < 4; ++j)
        #pragma unroll
        for (int f = 0; f < 4; ++f) a[j][f] = 0.f;

    for (int eb = r0; eb < r4; eb += 64) {
        unsigned int pe = edge[min(eb + lane, r4 - 1)];
        #pragma unroll
        for (int k = 0; k < 4; ++k) {
            int s   = k * 16 + g;
            int idx = eb + s;
            unsigned int ue = __shfl(pe, s);
            int   srcn = (int)(ue >> 16);
            float w = (idx < r4) ? edge_w(ue) : 0.f;
            int nid = (idx >= r1) + (idx >= r2) + (idx >= r3);
            float4 vv = zin4[(size_t)srcn * 4 + c];
            #pragma unroll
            for (int j = 0; j < 4; ++j) {
                float sel = (nid == j) ? w : 0.f;
                a[j][0] = fmaf(sel, vv.x, a[j][0]);
                a[j][1] = fmaf(sel, vv.y, a[j][1]);
                a[j][2] = fmaf(sel, vv.z, a[j][2]);
                a[j][3] = fmaf(sel, vv.w, a[j][3]);
            }
        }
    }

    #pragma unroll
    for (int j = 0; j < 4; ++j) {
        #pragma unroll
        for (int f = 0; f < 4; ++f) {
            a[j][f] += __shfl_xor(a[j][f], 4);
            a[j][f] += __shfl_xor(a[j][f], 8);
            a[j][f] += __shfl_xor(a[j][f], 16);
            a[j][f] += __shfl_xor(a[j][f], 32);
        }
    }

    if (g < 4 && n0 + g < n) {
        float o0 = (g == 0) ? a[0][0] : (g == 1) ? a[1][0] : (g == 2) ? a[2][0] : a[3][0];
        float o1 = (g == 0) ? a[0][1] : (g == 1) ? a[1][1] : (g == 2) ? a[2][1] : a[3][1];
        float o2 = (g == 0) ? a[0][2] : (g == 1) ? a[1][2] : (g == 2) ? a[2][2] : a[3][2];
        float o3 = (g == 0) ? a[0][3] : (g == 1) ? a[1][3] : (g == 2) ? a[2][3] : a[3][3];
        float4 o;
        o.x = o0 * DIFF + (1.f - DIFF) * h.x;
        o.y = o1 * DIFF + (1.f - DIFF) * h.y;
        o.z = o2 * DIFF + (1.f - DIFF) * h.z;
        o.w = o3 * DIFF + (1.f - DIFF) * h.w;
        zout4[(size_t)(n0 + g) * 4 + c] = o;
    }
}

// ---------------- fused pair-MLP + node-MLP, persistent, 16-node tiles ----------------

#define PM_GRID 768

__global__ __launch_bounds__(256) void k_pairmlp(const unsigned short* __restrict__ z1, const float* __restrict__ x,
                                                 const float* __restrict__ W1, const float* __restrict__ b1,
                                                 const float* __restrict__ W2, const float* __restrict__ b2,
                                                 const float* __restrict__ A1, const float* __restrict__ ab1,
                                                 const float* __restrict__ A2, const float* __restrict__ ab2,
                                                 const float* __restrict__ emb,
                                                 float* __restrict__ g0, int n, int ntiles) {
    __shared__ float W1s[128 * 64];
    __shared__ float W2s[64 * 16];
    __shared__ float in_s[16][128];
    __shared__ float hid[16 * 65];
    __shared__ float eA1T[ADJ_HID * 64];
    __shared__ float a0s[ADJ_HID], a1s[ADJ_HID], a2s[ADJ_HID];
    __shared__ float ab2s;

    int tid = threadIdx.x;
    const ushort4* z4p = (const ushort4*)z1;
    const float4*  x4p = (const float4*)x;

    #pragma unroll
    for (int k = 0; k < 32; ++k) W1s[tid + k * 256] = W1[tid + k * 256];
    #pragma unroll
    for (int k = 0; k < 4; ++k)  W2s[tid + k * 256] = W2[tid + k * 256];
    if (tid < ADJ_HID) { a0s[tid] = A1[tid]; a1s[tid] = A1[ADJ_HID + tid]; a2s[tid] = A2[tid]; }
    if (tid == 0) ab2s = ab2[0];
    for (int idx = tid; idx < ADJ_HID * 64; idx += 256) {
        int h = idx >> 6, c = idx & 63;
        float s = ab1[h];
        #pragma unroll
        for (int j = 0; j < EMB_DIM; j++) s = fmaf(emb[c * EMB_DIM + j], A1[(2 + j) * ADJ_HID + h], s);
        eA1T[idx] = s;
    }
    __syncthreads();

    for (int tile = blockIdx.x; tile < ntiles; tile += PM_GRID) {
        int base = tile * 16;

        {
            int nl = tid >> 4, c4 = tid & 15;
            int node = base + nl; if (node > n - 1) node = n - 1;
            ushort4 z4 = z4p[(size_t)node * 16 + c4];
            float4  x4 = x4p[(size_t)node * 16 + c4];
            float zf0 = bf2f(z4.x), zf1 = bf2f(z4.y), zf2 = bf2f(z4.z), zf3 = bf2f(z4.w);
            float o0 = ab2s, o1 = ab2s, o2 = ab2s, o3 = ab2s;
            #pragma unroll
            for (int h = 0; h < ADJ_HID; h++) {
                float a0 = a0s[h], a1 = a1s[h], a2 = a2s[h];
                float4 ee = *(const float4*)&eA1T[h * 64 + c4 * 4];
                float t;
                t = fmaf(zf0, a0, fmaf(x4.x, a1, ee.x)); t = fmaxf(t, 0.f); o0 = fmaf(t, a2, o0);
                t = fmaf(zf1, a0, fmaf(x4.y, a1, ee.y)); t = fmaxf(t, 0.f); o1 = fmaf(t, a2, o1);
                t = fmaf(zf2, a0, fmaf(x4.z, a1, ee.z)); t = fmaxf(t, 0.f); o2 = fmaf(t, a2, o2);
                t = fmaf(zf3, a0, fmaf(x4.w, a1, ee.w)); t = fmaxf(t, 0.f); o3 = fmaf(t, a2, o3);
            }
            *(float4*)&in_s[nl][c4 * 4]      = make_float4(o0 * 0.5f, o1 * 0.5f, o2 * 0.5f, o3 * 0.5f);
            *(float4*)&in_s[nl][64 + c4 * 4] = x4;
        }
        __syncthreads();

        {
            int lane = tid & 63, wv = tid >> 6;
            int nb0 = wv * 4;
            float bv = b1[lane];
            float acc[4];
            #pragma unroll
            for (int j = 0; j < 4; ++j) acc[j] = bv;
            #pragma unroll 8
            for (int rb = 0; rb < 128; rb += 4) {
                float w0 = W1s[(rb    ) * 64 + lane];
                float w1 = W1s[(rb + 1) * 64 + lane];
                float w2 = W1s[(rb + 2) * 64 + lane];
                float w3 = W1s[(rb + 3) * 64 + lane];
                #pragma unroll
                for (int j = 0; j < 4; ++j) {
                    float4 iv = *(const float4*)&in_s[nb0 + j][rb];
                    acc[j] = fmaf(iv.w, w3, fmaf(iv.z, w2, fmaf(iv.y, w1, fmaf(iv.x, w0, acc[j]))));
                }
            }
            #pragma unroll
            for (int j = 0; j < 4; ++j) hid[(nb0 + j) * 65 + lane] = fmaxf(acc[j], 0.f);
        }
        __syncthreads();

        {
            int c  = tid & 15;
            int nl = tid >> 4;
            float ac = b2[c];
            #pragma unroll
            for (int h = 0; h < 64; ++h)
                ac = fmaf(hid[nl * 65 + h], W2s[h * 16 + c], ac);
            int n0 = base + nl;
            if (n0 < n) g0[(size_t)n0 * 16 + c] = ac;
        }
        __syncthreads();
    }
}

// ---------------- launch ----------------

extern "C" void kernel_launch(void* const* d_in, const int* in_sizes, int n_in,
                              void* d_out, int out_size, void* d_ws, size_t ws_size,
                              hipStream_t stream) {
    const float* x   = (const float*)d_in[0];
    const int*   src = (const int*)d_in[1];
    const int*   dst = (const int*)d_in[2];
    const float* W1  = (const float*)d_in[3];
    const float* b1  = (const float*)d_in[4];
    const float* W2  = (const float*)d_in[5];
    const float* b2  = (const float*)d_in[6];
    const float* A1  = (const float*)d_in[7];
    const float* ab1 = (const float*)d_in[8];
    const float* A2  = (const float*)d_in[9];
    const float* ab2 = (const float*)d_in[10];
    const float* emb = (const float*)d_in[11];

    int n = in_sizes[0] / FEATS;   // 50000
    int e = in_sizes[1];           // 800000

    char* ws = (char*)d_ws;
    size_t off = 0;
    auto alloc = [&](size_t bytes) {
        void* p = ws + off;
        off += bytes;
        off = (off + 255) & ~(size_t)255;
        return p;
    };

    int*          deg    = (int*)          alloc((size_t)n * 4);
    float*        invs   = (float*)        alloc((size_t)n * 4);
    int*          rowptr = (int*)          alloc((size_t)(n + 1) * 4);
    int*          cnt    = (int*)          alloc((size_t)n * 4);
    int*          bsum   = (int*)          alloc(1024);
    unsigned int* edge   = (unsigned int*) alloc((size_t)e * 4 + 256);
    ushort4*      xb     = (ushort4*)      alloc((size_t)n * 64 * 2);
    ushort4*      zbA    = (ushort4*)      alloc((size_t)n * 64 * 2);
    ushort4*      zbB    = (ushort4*)      alloc((size_t)n * 64 * 2);
    float*        g0     = (float*)        alloc((size_t)n * 16 * 4);
    float*        g1     = (float*)        alloc((size_t)n * 16 * 4);
    float*        g2     = (float*)        alloc((size_t)n * 16 * 4);

    hipMemsetAsync(deg, 0, (size_t)n * 4, stream);
    hipMemsetAsync(cnt, 0, (size_t)n * 4, stream);

    int eb = (e + 255) / 256;
    int nb = (n + 255) / 256;

    k_deg    <<<eb, 256, 0, stream>>>(dst, deg, e);
    k_invs   <<<nb, 256, 0, stream>>>(deg, invs, n);
    k_scan1  <<<nb, 256, 0, stream>>>(deg, rowptr, bsum, n);
    k_scan2  <<<1, 256, 0, stream>>>(bsum, nb);
    k_scan3  <<<(n + 256) / 256, 256, 0, stream>>>(rowptr, bsum, n, e);
    k_scatter<<<1024, 256, 0, stream>>>(src, dst, invs, rowptr, cnt, edge, e, n);

    int total4 = n * 16;
    k_cast<<<(total4 + 255) / 256, 256, 0, stream>>>((const float4*)x, xb, total4);

    int nquad = (n + 3) / 4;
    int cblocks = (nquad + 3) / 4;   // 4 waves (node-quads) per 256-thread block

    // ---- diffusion loop 1 (bf16, 10 iters) ----
    const ushort4* zin = xb;
    ushort4* zout = zbA;
    for (int it = 0; it < 10; ++it) {
        k_conv64b<<<cblocks, 256, 0, stream>>>(zin, xb, zout, rowptr, edge, n);
        zin  = zout;
        zout = (it == 0) ? zbB : ((zout == zbA) ? zbB : zbA);
    }
    const unsigned short* z1 = (const unsigned short*)zin;

    int ntiles = (n + 15) / 16;
    k_pairmlp<<<PM_GRID, 256, 0, stream>>>(z1, x, W1, b1, W2, b2,
                                           A1, ab1, A2, ab2, emb, g0, n, ntiles);

    // ---- diffusion loop 2 (fp32, 10 iters) ----
    const float* gin = g0;
    float* gout = g1;
    for (int it = 0; it < 10; ++it) {
        float* out = (it == 9) ? (float*)d_out : gout;
        k_conv16<<<cblocks, 256, 0, stream>>>((const float4*)gin, (const float4*)g0, (float4*)out,
                                              rowptr, edge, n);
        gin  = out;
        gout = (gout == g1) ? g2 : g1;
    }
}